// Round 15
// baseline (119.568 us; speedup 1.0000x reference)
//
#include <hip/hip_runtime.h>
#include <math.h>

#define BB 8
#define CC 64
#define NN 4096
#define CI 8
#define GAMMA 0.1f
// exp(s/sqrt(8)) = exp2(s * log2(e)/sqrt(8)); folded into k in qkv.
#define SCALE (1.44269504088896f * 0.35355339059327f)
#define NSPLIT 8

typedef float v4f  __attribute__((ext_vector_type(4)));
typedef float v16f __attribute__((ext_vector_type(16)));
typedef __bf16 bf16x8 __attribute__((ext_vector_type(8)));
typedef __bf16 bf16x4 __attribute__((ext_vector_type(4)));
typedef unsigned int uint32;

__device__ __forceinline__ float fast_exp2(float x) {
    return __builtin_amdgcn_exp2f(x);
}
__device__ __forceinline__ uint32 fbits(float x) {
    return __builtin_bit_cast(uint32, x);
}
// Pack two f32 -> (bf16(hi)<<16)|bf16(lo), truncating (v_perm_b32, 1 op).
__device__ __forceinline__ uint32 pack_bf16(float lo, float hi) {
    return __builtin_amdgcn_perm(fbits(hi), fbits(lo), 0x07060302u);
}

// R7-proven qkv. Grid (NN/32, BB); block 256 = 8 i-groups x 32 n.
// qbh[b][n][8], kbh[b][m][8] (k*SCALE), vbh[b][i][N] bf16; zeros attab[b][9][N].
__global__ __launch_bounds__(256) void qkv_kernel(
        const float* __restrict__ x,
        const float* __restrict__ Wq, const float* __restrict__ Wk,
        const float* __restrict__ Wv,
        __bf16* __restrict__ qbh, __bf16* __restrict__ kbh,
        __bf16* __restrict__ vbh, float* __restrict__ attab) {
    __shared__ float sw[3 * CI * CC];     // 6 KB: Wq | Wk*SCALE | Wv
    __shared__ unsigned short sq[32 * 8]; // bf16 tile [n_local][i]
    __shared__ unsigned short sk[32 * 8];
    const int t = threadIdx.x;
    const int i  = t >> 5;
    const int nl = t & 31;
    const int b  = blockIdx.y;
    const int n0 = blockIdx.x * 32;

    for (int idx = t; idx < CI * CC; idx += 256) {
        sw[idx]                = Wq[idx];
        sw[CI * CC + idx]      = Wk[idx] * SCALE;
        sw[2 * CI * CC + idx]  = Wv[idx];
    }
    int lin = (blockIdx.y * (NN / 32) + blockIdx.x) * 256 + t;
    for (int idx = lin; idx < BB * 9 * NN; idx += BB * NN * CI) attab[idx] = 0.f;
    __syncthreads();

    const int n = n0 + nl;
    const float* xp = x + ((size_t)b * CC) * NN + n;
    const v4f* wq4 = (const v4f*)(sw + i * CC);
    const v4f* wk4 = (const v4f*)(sw + CI * CC + i * CC);
    const v4f* wv4 = (const v4f*)(sw + 2 * CI * CC + i * CC);
    float qa = 0.f, ka = 0.f, va = 0.f;
#pragma unroll 4
    for (int c4 = 0; c4 < CC / 4; ++c4) {
        v4f wq = wq4[c4], wk = wk4[c4], wv = wv4[c4];   // LDS broadcast b128
        float x0 = xp[(size_t)(c4 * 4 + 0) * NN];
        float x1 = xp[(size_t)(c4 * 4 + 1) * NN];
        float x2 = xp[(size_t)(c4 * 4 + 2) * NN];
        float x3 = xp[(size_t)(c4 * 4 + 3) * NN];
        qa = fmaf(wq.x, x0, qa); ka = fmaf(wk.x, x0, ka); va = fmaf(wv.x, x0, va);
        qa = fmaf(wq.y, x1, qa); ka = fmaf(wk.y, x1, ka); va = fmaf(wv.y, x1, va);
        qa = fmaf(wq.z, x2, qa); ka = fmaf(wk.z, x2, ka); va = fmaf(wv.z, x2, va);
        qa = fmaf(wq.w, x3, qa); ka = fmaf(wk.w, x3, ka); va = fmaf(wv.w, x3, va);
    }
    __bf16 vb = (__bf16)va;
    vbh[((size_t)b * CI + i) * NN + n] = vb;
    __bf16 qb = (__bf16)qa, kb2 = (__bf16)ka;
    sq[nl * 8 + i] = *(unsigned short*)&qb;
    sk[nl * 8 + i] = *(unsigned short*)&kb2;
    __syncthreads();
    if (t < 32) {
        *(uint4*)(qbh + ((size_t)b * NN + n0 + t) * 8) = *(const uint4*)(sq + t * 8);
        *(uint4*)(kbh + ((size_t)b * NN + n0 + t) * 8) = *(const uint4*)(sk + t * 8);
    }
}

// 32x32-tile MFMA attention, VALU-thinned (R14 skeleton; R14 measured
// ~320 VALU cyc/chunk vs ~40 visible ops -> codegen bloat was the bound).
// Changes vs R14, all issue-count cuts, numerics-equivalent:
//  1. E pack via v_perm_b32 truncation (1 op / 2 elems) replacing 16 scalar
//     bf16 casts + vector inserts.
//  2. E stored in MFMA-REG ORDER (n' = reg + 16*hi); PV's K-dim permuted
//     consistently (sum over k is permutation-invariant): v-frag = two b64
//     loads at base = 16*(quad&1)+4*(quad>>1), +8. Same 72B pitch (only
//     HW-validated 0-conflict pitch), same b64 widths.
//  3. qfrag load UNCONDITIONAL: kfragB==0 for k>=8 makes A's k>=8 moot.
//  4. vfrag: unconditional load + single lm==8 ones-override (D rows 9..15
//     are computed-but-discarded; rows are independent).
//  5. zero-C hoisted.
// Grid (NN/128, NSPLIT, BB) = 2048 blocks x 4 waves; wave = 32-m tile.
__global__ __launch_bounds__(256) void att_kernel(
        const __bf16* __restrict__ qbh, const __bf16* __restrict__ kbh,
        const __bf16* __restrict__ vbh, float* __restrict__ attab) {
    __shared__ unsigned short eld[4][32 * 36];  // per-wave tile, 72B pitch
    const int t = threadIdx.x;
    const int w    = t >> 6;
    const int l    = t & 63;
    const int ln   = l & 31;        // S: A-row (n) / B-col (m)
    const int hi   = l >> 5;        // S: k-half / C row-offset selector
    const int quad = l >> 4;        // PV: 16x16 quadrant
    const int lm   = l & 15;
    const int b  = blockIdx.z;
    const int m0 = blockIdx.x * 128 + w * 32;
    const int nbase = blockIdx.y * (NN / NSPLIT);   // 512 per wave
    const int NCH = (NN / NSPLIT) / 32;             // 16 chunks of 32 n

    bf16x8 zero8, ones8;
#pragma unroll
    for (int z = 0; z < 8; ++z) { zero8[z] = (__bf16)0.0f; ones8[z] = (__bf16)1.0f; }
    const v16f zeroC = {0.f,0.f,0.f,0.f,0.f,0.f,0.f,0.f,
                        0.f,0.f,0.f,0.f,0.f,0.f,0.f,0.f};

    // S B-frag (loop-invariant): B[k=hi*8+j][col=ln] = K[m0+ln][j], hi==0 live
    bf16x8 kfragB = hi ? zero8
                       : *(const bf16x8*)(kbh + ((size_t)b * NN + m0 + ln) * 8);

    const __bf16* qrow = qbh + (size_t)b * NN * 8 + (size_t)(nbase + ln) * 8;
    const int vbase = 16 * (quad & 1) + 4 * (quad >> 1);   // PV k-permutation
    const __bf16* vrowq = vbh + ((size_t)b * CI + (lm & 7)) * NN + nbase + vbase;
    const bool v_1 = (lm == 8);

    unsigned short* tile = eld[w];
    unsigned short* wr   = tile + ln * 36 + hi * 16;        // reg-order store
    const unsigned short* rd0 = tile + lm * 36 + quad * 8;
    const unsigned short* rd1 = tile + (16 + lm) * 36 + quad * 8;

    v4f acc0 = {0.f, 0.f, 0.f, 0.f};
    v4f acc1 = {0.f, 0.f, 0.f, 0.f};

    for (int ch = 0; ch < NCH; ++ch) {
        const int nc = ch * 32;
        // S A-frag: unconditional (see note 3)
        bf16x8 qfrag = *(const bf16x8*)(qrow + (size_t)nc * 8);
        // PV A-frag: permuted-k, two b64 loads (see note 2)
        bf16x4 vA = *(const bf16x4*)(vrowq + nc);
        bf16x4 vB = *(const bf16x4*)(vrowq + nc + 8);
        bf16x8 vfrag;
#pragma unroll
        for (int z = 0; z < 4; ++z) { vfrag[z] = vA[z]; vfrag[4 + z] = vB[z]; }
        vfrag = v_1 ? ones8 : vfrag;

        v16f S = __builtin_amdgcn_mfma_f32_32x32x16_bf16(qfrag, kfragB, zeroC, 0, 0, 0);

        // exp + truncating pack, reg order: short n'=r <- exp2(S[r])
        uint32 ep0 = pack_bf16(fast_exp2(S[0]),  fast_exp2(S[1]));
        uint32 ep1 = pack_bf16(fast_exp2(S[2]),  fast_exp2(S[3]));
        uint32 ep2 = pack_bf16(fast_exp2(S[4]),  fast_exp2(S[5]));
        uint32 ep3 = pack_bf16(fast_exp2(S[6]),  fast_exp2(S[7]));
        uint32 ep4 = pack_bf16(fast_exp2(S[8]),  fast_exp2(S[9]));
        uint32 ep5 = pack_bf16(fast_exp2(S[10]), fast_exp2(S[11]));
        uint32 ep6 = pack_bf16(fast_exp2(S[12]), fast_exp2(S[13]));
        uint32 ep7 = pack_bf16(fast_exp2(S[14]), fast_exp2(S[15]));
        *(uint2*)(wr)      = (uint2){ep0, ep1};   // ds_write_b64 x4, 72B pitch
        *(uint2*)(wr + 4)  = (uint2){ep2, ep3};
        *(uint2*)(wr + 8)  = (uint2){ep4, ep5};
        *(uint2*)(wr + 12) = (uint2){ep6, ep7};

        // PV B-frags: B[k'=quad*8+j][col] = tile[col][k'] (k' = n' storage idx)
        bf16x8 ef0 = *(const bf16x8*)(rd0);
        bf16x8 ef1 = *(const bf16x8*)(rd1);
        acc0 = __builtin_amdgcn_mfma_f32_16x16x32_bf16(vfrag, ef0, acc0, 0, 0, 0);
        acc1 = __builtin_amdgcn_mfma_f32_16x16x32_bf16(vfrag, ef1, acc1, 0, 0, 0);
    }

    // Epilogue: D[row=quad*4+r][col]; rows 0..7 = sum e*v_i, row 8 = sum e.
    float* ap = attab + (size_t)b * 9 * NN + m0;
    float a0[4] = {acc0.x, acc0.y, acc0.z, acc0.w};
    float a1[4] = {acc1.x, acc1.y, acc1.z, acc1.w};
#pragma unroll
    for (int r = 0; r < 4; ++r) {
        int i = quad * 4 + r;
        if (i < 9) {
            atomicAdd(ap + (size_t)i * NN + lm, a0[r]);
            atomicAdd(ap + (size_t)i * NN + 16 + lm, a1[r]);
        }
    }
}

// R7-proven out. Grid (NN/1024, CC, BB); block 256; float4 per thread.
__global__ __launch_bounds__(256) void out_kernel(
        const float* __restrict__ x, const float* __restrict__ Wout,
        const float* __restrict__ attab, float* __restrict__ out) {
    const int t = threadIdx.x;
    const int c = blockIdx.y;
    const int b = blockIdx.z;
    const int m = (blockIdx.x * 256 + t) * 4;
    const float* ap = attab + (size_t)b * 9 * NN + m;
    v4f sum = *(const v4f*)(ap + (size_t)8 * NN);
    v4f s = {0.f, 0.f, 0.f, 0.f};
#pragma unroll
    for (int i = 0; i < CI; ++i) {
        float wgt = Wout[c * CI + i];               // uniform -> s_load
        v4f a = *(const v4f*)(ap + (size_t)i * NN);
        s.x = fmaf(wgt, a.x, s.x);
        s.y = fmaf(wgt, a.y, s.y);
        s.z = fmaf(wgt, a.z, s.z);
        s.w = fmaf(wgt, a.w, s.w);
    }
    size_t o = ((size_t)b * CC + c) * NN + m;
    v4f xv = *(const v4f*)(x + o);
    v4f r;
    r.x = xv.x + GAMMA * (s.x / sum.x);
    r.y = xv.y + GAMMA * (s.y / sum.y);
    r.z = xv.z + GAMMA * (s.z / sum.z);
    r.w = xv.w + GAMMA * (s.w / sum.w);
    *(v4f*)(out + o) = r;
}

extern "C" void kernel_launch(void* const* d_in, const int* in_sizes, int n_in,
                              void* d_out, int out_size, void* d_ws, size_t ws_size,
                              hipStream_t stream) {
    const float* x    = (const float*)d_in[0];
    const float* Wq   = (const float*)d_in[1];
    const float* Wk   = (const float*)d_in[2];
    const float* Wv   = (const float*)d_in[3];
    const float* Wout = (const float*)d_in[4];
    float* out = (float*)d_out;

    // ws: qbh [B][N][8] bf16 | kbh [B][N][8] bf16 | vbh [B][8][N] bf16 |
    //     attab [B][9][N] fp32
    __bf16* qbh = (__bf16*)d_ws;
    __bf16* kbh = qbh + (size_t)BB * NN * 8;
    __bf16* vbh = kbh + (size_t)BB * NN * 8;
    float* attab = (float*)(vbh + (size_t)BB * NN * 8);

    qkv_kernel<<<dim3(NN / 32, BB), 256, 0, stream>>>(x, Wq, Wk, Wv, qbh, kbh, vbh, attab);
    att_kernel<<<dim3(NN / 128, NSPLIT, BB), 256, 0, stream>>>(qbh, kbh, vbh, attab);
    out_kernel<<<dim3(NN / 1024, CC, BB), 256, 0, stream>>>(x, Wout, attab, out);
}

// Round 16
// 114.107 us; speedup vs baseline: 1.0479x; 1.0479x over previous
//
#include <hip/hip_runtime.h>
#include <math.h>

#define BB 8
#define CC 64
#define NN 4096
#define CI 8
#define GAMMA 0.1f
// exp(s/sqrt(8)) = exp2(s * log2(e)/sqrt(8)); folded into k in qkv.
#define SCALE (1.44269504088896f * 0.35355339059327f)
#define NSPLIT 8

typedef float v4f  __attribute__((ext_vector_type(4)));
typedef float v16f __attribute__((ext_vector_type(16)));
typedef __bf16 bf16x8 __attribute__((ext_vector_type(8)));
typedef __bf16 bf16x4 __attribute__((ext_vector_type(4)));

__device__ __forceinline__ float fast_exp2(float x) {
    return __builtin_amdgcn_exp2f(x);
}

// R7-proven qkv. Grid (NN/32, BB); block 256 = 8 i-groups x 32 n.
// qbh[b][n][8], kbh[b][m][8] (k*SCALE), vbh[b][i][N] bf16; zeros attab[b][9][N].
__global__ __launch_bounds__(256) void qkv_kernel(
        const float* __restrict__ x,
        const float* __restrict__ Wq, const float* __restrict__ Wk,
        const float* __restrict__ Wv,
        __bf16* __restrict__ qbh, __bf16* __restrict__ kbh,
        __bf16* __restrict__ vbh, float* __restrict__ attab) {
    __shared__ float sw[3 * CI * CC];     // 6 KB: Wq | Wk*SCALE | Wv
    __shared__ unsigned short sq[32 * 8]; // bf16 tile [n_local][i]
    __shared__ unsigned short sk[32 * 8];
    const int t = threadIdx.x;
    const int i  = t >> 5;
    const int nl = t & 31;
    const int b  = blockIdx.y;
    const int n0 = blockIdx.x * 32;

    for (int idx = t; idx < CI * CC; idx += 256) {
        sw[idx]                = Wq[idx];
        sw[CI * CC + idx]      = Wk[idx] * SCALE;
        sw[2 * CI * CC + idx]  = Wv[idx];
    }
    int lin = (blockIdx.y * (NN / 32) + blockIdx.x) * 256 + t;
    for (int idx = lin; idx < BB * 9 * NN; idx += BB * NN * CI) attab[idx] = 0.f;
    __syncthreads();

    const int n = n0 + nl;
    const float* xp = x + ((size_t)b * CC) * NN + n;
    const v4f* wq4 = (const v4f*)(sw + i * CC);
    const v4f* wk4 = (const v4f*)(sw + CI * CC + i * CC);
    const v4f* wv4 = (const v4f*)(sw + 2 * CI * CC + i * CC);
    float qa = 0.f, ka = 0.f, va = 0.f;
#pragma unroll 4
    for (int c4 = 0; c4 < CC / 4; ++c4) {
        v4f wq = wq4[c4], wk = wk4[c4], wv = wv4[c4];   // LDS broadcast b128
        float x0 = xp[(size_t)(c4 * 4 + 0) * NN];
        float x1 = xp[(size_t)(c4 * 4 + 1) * NN];
        float x2 = xp[(size_t)(c4 * 4 + 2) * NN];
        float x3 = xp[(size_t)(c4 * 4 + 3) * NN];
        qa = fmaf(wq.x, x0, qa); ka = fmaf(wk.x, x0, ka); va = fmaf(wv.x, x0, va);
        qa = fmaf(wq.y, x1, qa); ka = fmaf(wk.y, x1, ka); va = fmaf(wv.y, x1, va);
        qa = fmaf(wq.z, x2, qa); ka = fmaf(wk.z, x2, ka); va = fmaf(wv.z, x2, va);
        qa = fmaf(wq.w, x3, qa); ka = fmaf(wk.w, x3, ka); va = fmaf(wv.w, x3, va);
    }
    __bf16 vb = (__bf16)va;
    vbh[((size_t)b * CI + i) * NN + n] = vb;
    __bf16 qb = (__bf16)qa, kb2 = (__bf16)ka;
    sq[nl * 8 + i] = *(unsigned short*)&qb;
    sk[nl * 8 + i] = *(unsigned short*)&kb2;
    __syncthreads();
    if (t < 32) {
        *(uint4*)(qbh + ((size_t)b * NN + n0 + t) * 8) = *(const uint4*)(sq + t * 8);
        *(uint4*)(kbh + ((size_t)b * NN + n0 + t) * 8) = *(const uint4*)(sk + t * 8);
    }
}

// 32x32-tile MFMA attention — R14 body (best measured, 41us) + PHASE-STAGGERED
// chunk order. R15 diagnosis: all pipes idle (VALU 33%, MFMA 7%, LDS 0-conf,
// HBM 4%) and ~40% of cycles NO wave ready -> the 8 waves/SIMD (from 8
// co-resident blocks, identical instruction streams, simultaneous start) run
// in LOCKSTEP and hit the LDS round-trip latency window together. Fix: each
// wave starts its chunk ring at a hashed offset (sum over n commutes ->
// numerics unchanged). Cost ~2 VALU/chunk.
// S C-layout (HW-verified): col=lane&31, row=(reg&3)+8*(reg>>2)+4*(lane>>5).
// Grid (NN/128, NSPLIT, BB) = 2048 blocks x 4 waves; wave = 32-m tile.
__global__ __launch_bounds__(256) void att_kernel(
        const __bf16* __restrict__ qbh, const __bf16* __restrict__ kbh,
        const __bf16* __restrict__ vbh, float* __restrict__ attab) {
    __shared__ unsigned short eld[4][32 * 36];  // per-wave tile, 72B pitch
    const int t = threadIdx.x;
    const int w    = t >> 6;
    const int l    = t & 63;
    const int ln   = l & 31;        // S: A-row (n) / B-col (m); C col (m)
    const int hi   = l >> 5;        // S: k-half selector (k = hi*8 + j)
    const int quad = l >> 4;        // PV: 16x16 quadrant
    const int lm   = l & 15;
    const int b  = blockIdx.z;
    const int m0 = blockIdx.x * 128 + w * 32;
    const int nbase = blockIdx.y * (NN / NSPLIT);   // 512 per wave
    const int NCH = (NN / NSPLIT) / 32;             // 16 chunks of 32 n
    // de-phase co-resident waves (accumulation order over n is irrelevant)
    const int phase = (blockIdx.x * 5 + blockIdx.y * 3 + w * 7) & (NCH - 1);

    bf16x8 zero8, ones8;
#pragma unroll
    for (int z = 0; z < 8; ++z) { zero8[z] = (__bf16)0.0f; ones8[z] = (__bf16)1.0f; }
    const v16f zeroC = {0.f,0.f,0.f,0.f,0.f,0.f,0.f,0.f,
                        0.f,0.f,0.f,0.f,0.f,0.f,0.f,0.f};

    // S B-frag (loop-invariant): B[k=hi*8+j][col=ln] = K[m0+ln][j], hi==0 live
    bf16x8 kfragB = hi ? zero8
                       : *(const bf16x8*)(kbh + ((size_t)b * NN + m0 + ln) * 8);

    const __bf16* qrow = qbh + (size_t)b * NN * 8;
    const __bf16* vrow = vbh + ((size_t)b * CI + (lm & 7)) * NN;
    const bool v_v = (lm < 8);
    const bool v_1 = (lm == 8);

    unsigned short* tile = eld[w];
    unsigned short* wr   = tile + ln * 36 + hi * 4;   // write base for this lane
    const unsigned short* rd0 = tile + lm * 36 + quad * 8;
    const unsigned short* rd1 = tile + (16 + lm) * 36 + quad * 8;

    v4f acc0 = {0.f, 0.f, 0.f, 0.f};
    v4f acc1 = {0.f, 0.f, 0.f, 0.f};

    for (int cc = 0; cc < NCH; ++cc) {
        const int ch = (cc + phase) & (NCH - 1);
        const int nc = nbase + ch * 32;
        // S A-frag: A[row=ln][k=hi*8+j] = Q[nc+ln][j], hi==0 live
        bf16x8 qfrag = hi ? zero8
                          : *(const bf16x8*)(qrow + (size_t)(nc + ln) * 8);
        // PV A-frag: A[row=lm][k=quad*8+j] = v_i[nc+quad*8+j] | ones | zero
        bf16x8 vfrag = v_v ? *(const bf16x8*)(vrow + nc + quad * 8)
                           : (v_1 ? ones8 : zero8);

        v16f S = __builtin_amdgcn_mfma_f32_32x32x16_bf16(qfrag, kfragB, zeroC, 0, 0, 0);

        // E: reg r -> n_local = (r&3) + 8*(r>>2) + 4*hi, col m = m0+ln.
        // Write 4 runs of 4 (ds_write_b64) into tile[m=ln][n]:
#pragma unroll
        for (int g = 0; g < 4; ++g) {
            bf16x4 e;
            e[0] = (__bf16)fast_exp2(S[4 * g + 0]);
            e[1] = (__bf16)fast_exp2(S[4 * g + 1]);
            e[2] = (__bf16)fast_exp2(S[4 * g + 2]);
            e[3] = (__bf16)fast_exp2(S[4 * g + 3]);
            *(bf16x4*)(wr + g * 8) = e;
        }

        // PV B-frags: B[k=quad*8+j][col=lm] = tile[m_half][quad*8+j]
        bf16x8 ef0 = *(const bf16x8*)(rd0);
        bf16x8 ef1 = *(const bf16x8*)(rd1);
        acc0 = __builtin_amdgcn_mfma_f32_16x16x32_bf16(vfrag, ef0, acc0, 0, 0, 0);
        acc1 = __builtin_amdgcn_mfma_f32_16x16x32_bf16(vfrag, ef1, acc1, 0, 0, 0);
    }

    // Epilogue: D[row=quad*4+r][col=lm]; rows 0..7 = sum e*v_i, row 8 = sum e.
    float* ap = attab + (size_t)b * 9 * NN + m0;
    float a0[4] = {acc0.x, acc0.y, acc0.z, acc0.w};
    float a1[4] = {acc1.x, acc1.y, acc1.z, acc1.w};
#pragma unroll
    for (int r = 0; r < 4; ++r) {
        int i = quad * 4 + r;
        if (i < 9) {
            atomicAdd(ap + (size_t)i * NN + lm, a0[r]);
            atomicAdd(ap + (size_t)i * NN + 16 + lm, a1[r]);
        }
    }
}

// R7-proven out. Grid (NN/1024, CC, BB); block 256; float4 per thread.
__global__ __launch_bounds__(256) void out_kernel(
        const float* __restrict__ x, const float* __restrict__ Wout,
        const float* __restrict__ attab, float* __restrict__ out) {
    const int t = threadIdx.x;
    const int c = blockIdx.y;
    const int b = blockIdx.z;
    const int m = (blockIdx.x * 256 + t) * 4;
    const float* ap = attab + (size_t)b * 9 * NN + m;
    v4f sum = *(const v4f*)(ap + (size_t)8 * NN);
    v4f s = {0.f, 0.f, 0.f, 0.f};
#pragma unroll
    for (int i = 0; i < CI; ++i) {
        float wgt = Wout[c * CI + i];               // uniform -> s_load
        v4f a = *(const v4f*)(ap + (size_t)i * NN);
        s.x = fmaf(wgt, a.x, s.x);
        s.y = fmaf(wgt, a.y, s.y);
        s.z = fmaf(wgt, a.z, s.z);
        s.w = fmaf(wgt, a.w, s.w);
    }
    size_t o = ((size_t)b * CC + c) * NN + m;
    v4f xv = *(const v4f*)(x + o);
    v4f r;
    r.x = xv.x + GAMMA * (s.x / sum.x);
    r.y = xv.y + GAMMA * (s.y / sum.y);
    r.z = xv.z + GAMMA * (s.z / sum.z);
    r.w = xv.w + GAMMA * (s.w / sum.w);
    *(v4f*)(out + o) = r;
}

extern "C" void kernel_launch(void* const* d_in, const int* in_sizes, int n_in,
                              void* d_out, int out_size, void* d_ws, size_t ws_size,
                              hipStream_t stream) {
    const float* x    = (const float*)d_in[0];
    const float* Wq   = (const float*)d_in[1];
    const float* Wk   = (const float*)d_in[2];
    const float* Wv   = (const float*)d_in[3];
    const float* Wout = (const float*)d_in[4];
    float* out = (float*)d_out;

    // ws: qbh [B][N][8] bf16 | kbh [B][N][8] bf16 | vbh [B][8][N] bf16 |
    //     attab [B][9][N] fp32
    __bf16* qbh = (__bf16*)d_ws;
    __bf16* kbh = qbh + (size_t)BB * NN * 8;
    __bf16* vbh = kbh + (size_t)BB * NN * 8;
    float* attab = (float*)(vbh + (size_t)BB * NN * 8);

    qkv_kernel<<<dim3(NN / 32, BB), 256, 0, stream>>>(x, Wq, Wk, Wv, qbh, kbh, vbh, attab);
    att_kernel<<<dim3(NN / 128, NSPLIT, BB), 256, 0, stream>>>(qbh, kbh, vbh, attab);
    out_kernel<<<dim3(NN / 1024, CC, BB), 256, 0, stream>>>(x, Wout, attab, out);
}